// Round 11
// baseline (97.148 us; speedup 1.0000x reference)
//
#include <hip/hip_runtime.h>
#include <math.h>

// Problem constants
#define BB   2
#define SS   1024
#define HH   1024
#define NHH  16
#define SPc  0.05f
#define EPSc 1e-5f

typedef unsigned short u16;
typedef unsigned int   u32;
using bf16x8 = __attribute__((ext_vector_type(8))) __bf16;
using f32x4  = __attribute__((ext_vector_type(4))) float;

// round-to-nearest-even fp32 -> bf16 bits (finite values only)
__device__ __forceinline__ u16 f2bf(float f) {
    u32 u = __builtin_bit_cast(u32, f);
    u32 r = u + 0x7fffu + ((u >> 16) & 1u);
    return (u16)(r >> 16);
}

// async global->LDS, 16B per lane. lds must be the wave-uniform base
// (HW writes base + lane*16); g is the per-lane global source.
__device__ __forceinline__ void async16(void* lds, const void* g) {
    __builtin_amdgcn_global_load_lds((const __attribute__((address_space(1))) u32*)g,
                                     (__attribute__((address_space(3))) u32*)lds,
                                     16, 0, 0);
}

__device__ __forceinline__ bf16x8 ldb8(const u16* p) {
    return *(const bf16x8*)(const void*)p;
}

// ---------------------------------------------------------------------------
// PREP (one launch, flat grid of 7248 blocks x 256):
//   [0,6144)      conv_a: q/k/v fp32 -> bf16
//   [6144,7168)   conv_w: W fp32 [k][n] -> bf16 Wt [n][k] (4 weights x 256 tiles)
//   [7168,7184)   msb per-head mean
//   [7184,7248)   seqmean partials of query
// ---------------------------------------------------------------------------
__global__ __launch_bounds__(256) void prep_kernel(
    const float* __restrict__ query, const float* __restrict__ key_t,
    const float* __restrict__ value,
    u16* __restrict__ Aq, u16* __restrict__ Ak, u16* __restrict__ Av,
    const float* __restrict__ W0, const float* __restrict__ W1,
    const float* __restrict__ W2, const float* __restrict__ W3,
    u16* __restrict__ T0, u16* __restrict__ T1,
    u16* __restrict__ T2, u16* __restrict__ T3,
    const float* __restrict__ msb, float* __restrict__ msbh,
    float* __restrict__ spp) {
    const int t = threadIdx.x;
    const int d = blockIdx.x;

    if (d < 6144) {                       // ---- conv_a ----
        const int which = d >> 11;
        const int bx    = d & 2047;
        const float* s; u16* dst;
        if (which == 0)      { s = query; dst = Aq; }
        else if (which == 1) { s = key_t; dst = Ak; }
        else                 { s = value; dst = Av; }
        const size_t i = ((size_t)bx * 256 + t) * 4;
        const float4 v = *(const float4*)(s + i);
        ushort4 o;
        o.x = f2bf(v.x); o.y = f2bf(v.y); o.z = f2bf(v.z); o.w = f2bf(v.w);
        *(ushort4*)(dst + i) = o;
        return;
    }
    if (d < 7168) {                       // ---- conv_w ----
        const int e  = d - 6144;
        const int wz = e >> 8;
        const int k0 = ((e >> 4) & 15) << 6;
        const int n0 = (e & 15) << 6;
        const float* W; u16* T;
        if (wz == 0)      { W = W0; T = T0; }
        else if (wz == 1) { W = W1; T = T1; }
        else if (wz == 2) { W = W2; T = T2; }
        else              { W = W3; T = T3; }
        __shared__ u16 tile[64][72];
        #pragma unroll
        for (int i = 0; i < 4; ++i) {
            const int chunk = i * 256 + t;
            const int r  = chunk >> 4;
            const int c4 = (chunk & 15) << 2;
            const float4 v = *(const float4*)(W + (size_t)(k0 + r) * 1024 + n0 + c4);
            tile[c4 + 0][r] = f2bf(v.x);
            tile[c4 + 1][r] = f2bf(v.y);
            tile[c4 + 2][r] = f2bf(v.z);
            tile[c4 + 3][r] = f2bf(v.w);
        }
        __syncthreads();
        #pragma unroll
        for (int i = 0; i < 4; ++i) {
            const int chunk = i * 256 + t;
            const int rn = chunk >> 4;
            const int ck = (chunk & 15) << 2;
            ushort4 o;
            o.x = tile[rn][ck + 0];
            o.y = tile[rn][ck + 1];
            o.z = tile[rn][ck + 2];
            o.w = tile[rn][ck + 3];
            *(ushort4*)(T + (size_t)(n0 + rn) * 1024 + k0 + ck) = o;
        }
        return;
    }
    if (d < 7184) {                       // ---- msb mean ----
        const int h = d - 7168;
        const float* p = msb + (size_t)h * 4096;
        float s = 0.f;
        for (int i = t; i < 4096; i += 256) s += p[i];
        __shared__ float red[256];
        red[t] = s;
        __syncthreads();
        for (int off = 128; off > 0; off >>= 1) {
            if (t < off) red[t] += red[t + off];
            __syncthreads();
        }
        if (t == 0) msbh[h] = red[0] * (1.f / 4096.f);
        return;
    }
    {                                     // ---- seqmean partials ----
        const int e = d - 7184;           // x:4, b:2, z:8
        const int x = e & 3;
        const int b = (e >> 2) & 1;
        const int z = e >> 3;
        const int h = x * 256 + t;
        const float* p = query + ((size_t)b * SS + (size_t)z * 128) * HH + h;
        float s = 0.f;
        for (int i = 0; i < 128; ++i) s += p[(size_t)i * HH];
        spp[((size_t)z * BB + b) * HH + h] = s;
    }
}

// ---------------------------------------------------------------------------
// spec MLP layer 2 (h1 finish fused): block (oc, kc2, b). Writes partial
// pre-bias dots; attn adds bs2 + sigmoid + mean.
// ---------------------------------------------------------------------------
__global__ __launch_bounds__(256) void mlp2_part_kernel(
    const float* __restrict__ mp1, const float* __restrict__ bs1,
    const float* __restrict__ Ws2, float* __restrict__ mp2) {
    const int t   = threadIdx.x;
    const int oc  = blockIdx.x;
    const int kc2 = blockIdx.y;
    const int b   = blockIdx.z;
    __shared__ float x[128];
    if (t < 128) {
        const int j = kc2 * 128 + t;
        float a = bs1[j];
        #pragma unroll
        for (int kc = 0; kc < 8; ++kc) a += mp1[((size_t)kc * BB + b) * 512 + j];
        x[t] = fmaxf(a, 0.f);
    }
    __syncthreads();
    const int o = oc * 256 + t;
    float acc = 0.f;
    #pragma unroll 4
    for (int k2 = 0; k2 < 128; ++k2)
        acc += x[k2] * Ws2[(size_t)(kc2 * 128 + k2) * 1024 + o];
    mp2[((size_t)kc2 * BB + b) * 1024 + o] = acc;
}

// ---------------------------------------------------------------------------
// bf16 MFMA GEMM core: tile BM x BN, BK=64 (16 iters, 16 MFMA/iter/wave),
// 4 waves (2m x 2n), bf16 A/B via global_load_lds with pre-swizzled source.
// LDS row = 64 u16 = 8 chunks of 16B; swizzle chunk c ^= (r&7) (2-way max).
// mode: 0 = f32 out row-major, 1 = bf16 out row-major, 2 = bf16 out -> Vt[b,h,d,s]
// ---------------------------------------------------------------------------
template<int BM, int BN>
__device__ __forceinline__ void gemm_core(const u16* __restrict__ A,
                                          const u16* __restrict__ Bt,
                                          const float* __restrict__ bias,
                                          void* __restrict__ Cout, int mode,
                                          int m0, int n0) {
    constexpr int FI = BM / 32;       // m-frags per wave
    constexpr int FJ = BN / 32;       // n-frags per wave
    __shared__ u16 sA[2][BM * 64];
    __shared__ u16 sB[2][BN * 64];
    const int t  = threadIdx.x;
    const int l  = t & 63;
    const int wv = t >> 6;
    const int wm = wv >> 1, wn = wv & 1;
    const int wbase = t & ~63;
    const int ql = l & 15;
    const int g_ = l >> 4;

    f32x4 acc[FI][FJ];
    #pragma unroll
    for (int i = 0; i < FI; ++i)
        #pragma unroll
        for (int j = 0; j < FJ; ++j) acc[i][j] = (f32x4){0.f, 0.f, 0.f, 0.f};

    auto stage = [&](int buf, int k0) {
        #pragma unroll
        for (int ii = 0; ii < BM / 32; ++ii) {
            const int chunk = ii * 256 + t;
            const int r  = chunk >> 3, c = chunk & 7;
            const int cs = (c ^ (r & 7)) << 3;
            async16(&sA[buf][(ii * 256 + wbase) << 3],
                    A + (size_t)(m0 + r) * 1024 + k0 + cs);
        }
        #pragma unroll
        for (int ii = 0; ii < BN / 32; ++ii) {
            const int chunk = ii * 256 + t;
            const int r  = chunk >> 3, c = chunk & 7;
            const int cs = (c ^ (r & 7)) << 3;
            async16(&sB[buf][(ii * 256 + wbase) << 3],
                    Bt + (size_t)(n0 + r) * 1024 + k0 + cs);
        }
    };

    stage(0, 0);
    for (int kk = 0; kk < 16; ++kk) {
        const int cur = kk & 1;
        __syncthreads();                       // drain stage into cur, protect cur^1
        if (kk < 15) stage(cur ^ 1, (kk + 1) << 6);
        const u16* bufA = sA[cur];
        const u16* bufB = sB[cur];
        bf16x8 af[FI][2], bg[FJ][2];
        #pragma unroll
        for (int i = 0; i < FI; ++i) {
            const int ra = wm * (BM / 2) + i * 16 + ql;
            const u16* base = bufA + ra * 64;
            af[i][0] = ldb8(base + ((g_ ^ (ra & 7)) << 3));
            af[i][1] = ldb8(base + (((4 + g_) ^ (ra & 7)) << 3));
        }
        #pragma unroll
        for (int j = 0; j < FJ; ++j) {
            const int rb = wn * (BN / 2) + j * 16 + ql;
            const u16* base = bufB + rb * 64;
            bg[j][0] = ldb8(base + ((g_ ^ (rb & 7)) << 3));
            bg[j][1] = ldb8(base + (((4 + g_) ^ (rb & 7)) << 3));
        }
        __builtin_amdgcn_s_setprio(1);
        #pragma unroll
        for (int i = 0; i < FI; ++i)
            #pragma unroll
            for (int j = 0; j < FJ; ++j) {
                acc[i][j] = __builtin_amdgcn_mfma_f32_16x16x32_bf16(af[i][0], bg[j][0], acc[i][j], 0, 0, 0);
                acc[i][j] = __builtin_amdgcn_mfma_f32_16x16x32_bf16(af[i][1], bg[j][1], acc[i][j], 0, 0, 0);
            }
        __builtin_amdgcn_s_setprio(0);
    }

    // epilogue: C/D layout col=lane&15, row=(lane>>4)*4+reg
    const int coll = ql;
    const int rowg = g_ << 2;
    #pragma unroll
    for (int j = 0; j < FJ; ++j) {
        const int n = n0 + wn * (BN / 2) + j * 16 + coll;
        const float bs = bias[n];
        #pragma unroll
        for (int i = 0; i < FI; ++i) {
            const int mb = m0 + wm * (BM / 2) + i * 16 + rowg;
            if (mode == 0) {
                float* C = (float*)Cout;
                #pragma unroll
                for (int rr = 0; rr < 4; ++rr)
                    C[(size_t)(mb + rr) * 1024 + n] = acc[i][j][rr] + bs;
            } else if (mode == 1) {
                u16* C = (u16*)Cout;
                #pragma unroll
                for (int rr = 0; rr < 4; ++rr)
                    C[(size_t)(mb + rr) * 1024 + n] = f2bf(acc[i][j][rr] + bs);
            } else {
                // Vt[b][h=n>>6][d=n&63][s=mb..mb+3], 4 consecutive s -> 8B store
                u16* C = (u16*)Cout;
                const int bI = mb >> 10;
                const int s  = mb & 1023;
                ushort4 o;
                o.x = f2bf(acc[i][j][0] + bs);
                o.y = f2bf(acc[i][j][1] + bs);
                o.z = f2bf(acc[i][j][2] + bs);
                o.w = f2bf(acc[i][j][3] + bs);
                *(ushort4*)(C + ((size_t)(bI * NHH + (n >> 6)) * 64 + (n & 63)) * 1024 + s) = o;
            }
        }
    }
}

// QKV GEMM (768 blocks, XCD-chunked) + mlp1 (32 trailing blocks).
__global__ __launch_bounds__(256, 3) void gemm_qkv_kernel(
    const u16* __restrict__ Aq, const u16* __restrict__ Ak, const u16* __restrict__ Av,
    const u16* __restrict__ WtQ, const u16* __restrict__ WtK, const u16* __restrict__ WtV,
    const float* __restrict__ bq, const float* __restrict__ bk, const float* __restrict__ bv,
    u16* __restrict__ Qbf, u16* __restrict__ Kbf, u16* __restrict__ Vt,
    const float* __restrict__ spp, const float* __restrict__ Ws1,
    float* __restrict__ mp1) {
    const int d = (int)blockIdx.x;
    if (d >= 768) {                       // ---- mlp1 partials ----
        const int e  = d - 768;           // jc:2, kc:8, b:2
        const int jc = e & 1;
        const int kc = (e >> 1) & 7;
        const int b  = e >> 4;
        const int t  = threadIdx.x;
        __shared__ float x[128];
        if (t < 128) {
            const int k = kc * 128 + t;
            float s = 0.f;
            #pragma unroll
            for (int z = 0; z < 8; ++z) s += spp[((size_t)z * BB + b) * HH + k];
            x[t] = s * (1.f / (float)SS);
        }
        __syncthreads();
        const int j = jc * 256 + t;
        float acc = 0.f;
        #pragma unroll 4
        for (int k2 = 0; k2 < 128; ++k2)
            acc += x[k2] * Ws1[(size_t)(kc * 128 + k2) * 512 + j];
        mp1[((size_t)kc * BB + b) * 512 + j] = acc;
        return;
    }
    const int g = (d & 7) * 96 + (d >> 3);       // bijective: 768 = 8 * 96
    const int n0 = (g & 7) << 7;
    const int m0 = ((g >> 3) & 31) << 6;
    const int zz = g >> 8;
    if (zz == 0)      gemm_core<64, 128>(Aq, WtQ, bq, Qbf, 1, m0, n0);
    else if (zz == 1) gemm_core<64, 128>(Ak, WtK, bk, Kbf, 1, m0, n0);
    else              gemm_core<64, 128>(Av, WtV, bv, Vt, 2, m0, n0);
}

// O-proj: BM=64, BN=64, grid 512 blocks, XCD-chunked swizzle.
__global__ __launch_bounds__(256, 3) void gemm_o_kernel(
    const u16* __restrict__ A, const u16* __restrict__ Bt,
    const float* __restrict__ bias, float* __restrict__ C) {
    const int d = (int)blockIdx.x + ((int)blockIdx.y << 4);
    const int g = (d & 7) * 64 + (d >> 3);       // bijective: 512 = 8 * 64
    const int n0 = (g & 15) << 6;
    const int m0 = (g >> 4) << 6;
    gemm_core<64, 64>(A, Bt, bias, C, 0, m0, n0);
}

// ---------------------------------------------------------------------------
// Flash attention, bf16 MFMA, swapped QK^T, IN-REGISTER P (permuted K rows).
// 4 waves x 16 q rows (QBLK=64). spec scalar computed per-wave (shuffle
// reduce, no barriers) from mp2 (+bs2), overlapped with first K/V staging.
// Gate+scale folded to quartic: v = A*raw + B*raw^2 - D*raw^4.
// Grid (S/64, NH, B) = 512 blocks, 256 threads.
// ---------------------------------------------------------------------------
__global__ __launch_bounds__(256, 2) void attn_mfma_kernel(
    const u16* __restrict__ Qbf, const u16* __restrict__ Kbf,
    const u16* __restrict__ Vt, const float* __restrict__ msbh,
    const float* __restrict__ mp2, const float* __restrict__ bs2,
    u16* __restrict__ ctx) {
    __shared__ u16 sK[2][4096];
    __shared__ u16 sV[2][4096];

    const int t  = threadIdx.x;     // 0..255
    const int l  = t & 63;
    const int wv = t >> 6;          // 0..3
    const int wbase = t & ~63;
    const int qt = blockIdx.x, h = blockIdx.y, b = blockIdx.z;
    const int ql = l & 15;          // this lane's q row (within wave's 16)
    const int g_ = l >> 4;          // lane group 0..3

    const u16* Kg = Kbf + (size_t)b * SS * HH + h * 64;
    const u16* Vg = Vt + (size_t)(b * NHH + h) * 64 * SS;   // rows d, cols s

    // Q fragments direct from global (L2-resident)
    const u16* qrow = Qbf + ((size_t)(b * SS + qt * 64 + wv * 16 + ql)) * HH + h * 64;
    const bf16x8 qf0 = ldb8(qrow + (g_ << 3));
    const bf16x8 qf1 = ldb8(qrow + ((4 + g_) << 3));

    // staging offsets (constant across kt); 2 chunks per thread per K and V
    int koff[2], vof[2], lof[2];
    #pragma unroll
    for (int ii = 0; ii < 2; ++ii) {
        const int chunk = ii * 256 + t;
        const int r = chunk >> 3, c = chunk & 7;
        // perm: LDS row r holds K seq row perm(r) (PV k-sum is perm-invariant)
        const int rp = (r & 3) | (((r >> 2) & 3) << 3) | (((r >> 4) & 1) << 2) | (r & 32);
        const int cs = (c ^ (r & 7)) << 3;
        koff[ii] = rp * 1024 + cs;
        vof[ii]  = r * 1024 + cs;
        lof[ii]  = (ii * 256 + wbase) << 3;
    }

#define KVSTAGE(buf, kt)                                                        \
    {                                                                           \
        _Pragma("unroll")                                                       \
        for (int ii = 0; ii < 2; ++ii) {                                        \
            async16(sK[buf] + lof[ii], Kg + ((size_t)(kt) << 16) + koff[ii]);   \
            async16(sV[buf] + lof[ii], Vg + ((kt) << 6) + vof[ii]);             \
        }                                                                       \
    }

    KVSTAGE(0, 0)

    // ---- per-wave spec: mean over o of sigmoid(sum_kc mp2 + bs2) ----
    // Each wave computes all 1024 terms (16/lane) + shuffle reduce: no
    // barriers, so the KV0 staging stays in flight underneath.
    float ssum = 0.f;
    #pragma unroll
    for (int j = 0; j < 16; ++j) {
        const int o = (j << 6) + l;
        float a = bs2[o];
        #pragma unroll
        for (int kc = 0; kc < 4; ++kc) a += mp2[((size_t)kc * BB + b) * 1024 + o];
        ssum += 1.f / (1.f + __expf(-a));
    }
    #pragma unroll
    for (int off = 1; off < 64; off <<= 1) ssum += __shfl_xor(ssum, off);
    const float sp = ssum * (1.f / 1024.f);

    const float mh = msbh[h] * 0.125f;
    const float c2 = 0.125f * sp;
    const float c3 = 0.125f * sp * SPc;
    // v = raw*(c2 + c3*sigmoid(raw*mh)); sigmoid(x) ~= 0.5 + 0.25x - x^3/48
    // => v = Ac*raw + Bc*raw^2 - Dc*raw^4
    const float Ac = c2 + 0.5f * c3;
    const float Bc = 0.25f * c3 * mh;
    const float Dc = c3 * mh * mh * mh * (1.f / 48.f);

    f32x4 oacc[4];
    #pragma unroll
    for (int dt = 0; dt < 4; ++dt) oacc[dt] = (f32x4){0.f, 0.f, 0.f, 0.f};
    float lsum = 0.f;

    for (int kt = 0; kt < 16; ++kt) {
        const int cur = kt & 1;
        __syncthreads();                         // drain stage into cur; prev compute done
        if (kt < 15) KVSTAGE(cur ^ 1, kt + 1)

        const u16* bufK = sK[cur];
        const u16* bufV = sV[cur];

        // swapped QK^T: lane holds S[k-slots][q=ql]
        f32x4 sc[4];
        __builtin_amdgcn_s_setprio(1);
        #pragma unroll
        for (int f = 0; f < 4; ++f) {
            const int r = (f << 4) + ql;
            bf16x8 kfa = ldb8(bufK + r * 64 + ((g_ ^ (r & 7)) << 3));
            bf16x8 kfb = ldb8(bufK + r * 64 + (((4 + g_) ^ (r & 7)) << 3));
            f32x4 z = (f32x4){0.f, 0.f, 0.f, 0.f};
            z = __builtin_amdgcn_mfma_f32_16x16x32_bf16(kfa, qf0, z, 0, 0, 0);
            z = __builtin_amdgcn_mfma_f32_16x16x32_bf16(kfb, qf1, z, 0, 0, 0);
            sc[f] = z;
        }
        __builtin_amdgcn_s_setprio(0);

        // quartic gate + exp; build PV A-fragments in-register
        bf16x8 pf0, pf1;
        #pragma unroll
        for (int f = 0; f < 4; ++f) {
            #pragma unroll
            for (int rr = 0; rr < 4; ++rr) {
                const float raw = sc[f][rr];
                const float r2 = raw * raw;
                const float tt = fmaf(-Dc, r2, Bc);
                const float v  = fmaf(tt, r2, Ac * raw);
                const float p  = __expf(v);
                lsum += p;
                const __bf16 pbv = (__bf16)p;
                if (f == 0)      pf0[rr] = pbv;
                else if (f == 1) pf0[4 + rr] = pbv;
                else if (f == 2) pf1[rr] = pbv;
                else             pf1[4 + rr] = pbv;
            }
        }

        // PV: O[q][d] += P * V^T (B operand = Vt rows d, s-chunks)
        __builtin_amdgcn_s_setprio(1);
        #pragma unroll
        for (int dt = 0; dt < 4; ++dt) {
            const int r = (dt << 4) + ql;
            bf16x8 vf0 = ldb8(bufV + r * 64 + ((g_ ^ (r & 7)) << 3));
            bf16x8 vf1 = ldb8(bufV + r * 64 + (((4 + g_) ^ (r & 7)) << 3));
            oacc[dt] = __builtin_amdgcn_mfma_f32_16x16x32_bf16(pf0, vf0, oacc[dt], 0, 0, 0);
            oacc[dt] = __builtin_amdgcn_mfma_f32_16x16x32_bf16(pf1, vf1, oacc[dt], 0, 0, 0);
        }
        __builtin_amdgcn_s_setprio(0);
    }
#undef KVSTAGE

    // row sums: lanes {q, q+16, q+32, q+48} hold disjoint partials of row q
    lsum += __shfl_xor(lsum, 16);
    lsum += __shfl_xor(lsum, 32);

    float linv[4];
    #pragma unroll
    for (int rr = 0; rr < 4; ++rr) linv[rr] = 1.f / __shfl(lsum, (g_ << 2) + rr);

    // store ctx (bf16 row-major [b,s,h*64+d]); output rows m=(l>>4)*4+rr
    #pragma unroll
    for (int rr = 0; rr < 4; ++rr) {
        const int q = qt * 64 + wv * 16 + (g_ << 2) + rr;
        u16* crow = ctx + ((size_t)(b * SS + q)) * HH + h * 64;
        #pragma unroll
        for (int dt = 0; dt < 4; ++dt)
            crow[dt * 16 + ql] = f2bf(oacc[dt][rr] * linv[rr]);
    }
}

// ---------------------------------------------------------------------------
// residual + LayerNorm: out = LN(X + query) * g + b ; one block per row
// ---------------------------------------------------------------------------
__global__ __launch_bounds__(256) void ln_kernel(
    const float* __restrict__ X, const float* __restrict__ qin,
    const float* __restrict__ g, const float* __restrict__ be, float* __restrict__ out) {
    const int row = blockIdx.x;
    const int t   = threadIdx.x;
    const int d4  = t << 2;
    const float4 x4 = *(const float4*)(X + (size_t)row * HH + d4);
    const float4 q4 = *(const float4*)(qin + (size_t)row * HH + d4);
    float4 v;
    v.x = x4.x + q4.x;
    v.y = x4.y + q4.y;
    v.z = x4.z + q4.z;
    v.w = x4.w + q4.w;
    float s  = v.x + v.y + v.z + v.w;
    float sq = v.x * v.x + v.y * v.y + v.z * v.z + v.w * v.w;
    for (int off = 1; off < 64; off <<= 1) {
        s  += __shfl_xor(s, off);
        sq += __shfl_xor(sq, off);
    }
    __shared__ float rs[4], rq[4];
    const int w = t >> 6;
    if ((t & 63) == 0) { rs[w] = s; rq[w] = sq; }
    __syncthreads();
    s  = rs[0] + rs[1] + rs[2] + rs[3];
    sq = rq[0] + rq[1] + rq[2] + rq[3];
    const float mu   = s * (1.f / (float)HH);
    const float var  = sq * (1.f / (float)HH) - mu * mu;
    const float rstd = rsqrtf(var + EPSc);
    const float4 g4 = *(const float4*)(g + d4);
    const float4 b4 = *(const float4*)(be + d4);
    float4 o;
    o.x = (v.x - mu) * rstd * g4.x + b4.x;
    o.y = (v.y - mu) * rstd * g4.y + b4.y;
    o.z = (v.z - mu) * rstd * g4.z + b4.z;
    o.w = (v.w - mu) * rstd * g4.w + b4.w;
    *(float4*)(out + (size_t)row * HH + d4) = o;
}

// ---------------------------------------------------------------------------
extern "C" void kernel_launch(void* const* d_in, const int* in_sizes, int n_in,
                              void* d_out, int out_size, void* d_ws, size_t ws_size,
                              hipStream_t stream) {
    (void)in_sizes; (void)n_in; (void)out_size; (void)ws_size;
    const float* query = (const float*)d_in[0];
    const float* key_t = (const float*)d_in[1];
    const float* value = (const float*)d_in[2];
    const float* Wq  = (const float*)d_in[3];
    const float* bq  = (const float*)d_in[4];
    const float* Wk  = (const float*)d_in[5];
    const float* bk  = (const float*)d_in[6];
    const float* Wv  = (const float*)d_in[7];
    const float* bv  = (const float*)d_in[8];
    const float* msb = (const float*)d_in[9];
    const float* Ws1 = (const float*)d_in[10];
    const float* bs1 = (const float*)d_in[11];
    const float* Ws2 = (const float*)d_in[12];
    const float* bs2 = (const float*)d_in[13];
    const float* Wo  = (const float*)d_in[14];
    const float* bo  = (const float*)d_in[15];
    const float* lng = (const float*)d_in[16];
    const float* lnb = (const float*)d_in[17];
    float* out = (float*)d_out;

    // workspace carve (~36.2 MB)
    char* p = (char*)d_ws;
    u16* Aq    = (u16*)p;                 //  0- 4 MB (2M bf16)
    u16* Ak    = Aq + 2097152;            //  4- 8
    u16* Av    = Ak + 2097152;            //  8-12
    u16* WtQ   = Av + 2097152;            // 12-14 (1M bf16)
    u16* WtK   = WtQ + 1048576;           // 14-16
    u16* WtV   = WtK + 1048576;           // 16-18
    u16* WtO   = WtV + 1048576;           // 18-20
    u16* Qbf   = WtO + 1048576;           // 20-24
    u16* Kbf   = Qbf + 2097152;           // 24-28
    u16* Vt    = Kbf + 2097152;           // 28-32
    u16* ctxbf = Vt + 2097152;            // 32-36
    float* Obuf = (float*)Aq;             // reuse 0-8 MB (Aq/Ak dead after QKV GEMM)
    float* spp   = (float*)(p + 36 * 1024 * 1024);   // 16384 f
    float* mp1   = spp + 16384;           // 8*2*512 = 8192 f
    float* mp2   = mp1 + 8192;            // 4*2*1024 = 8192 f
    float* msbh  = mp2 + 8192;            // NH

    prep_kernel<<<dim3(7248), 256, 0, stream>>>(
        query, key_t, value, Aq, Ak, Av,
        Wq, Wk, Wv, Wo, WtQ, WtK, WtV, WtO, msb, msbh, spp);

    gemm_qkv_kernel<<<dim3(800), 256, 0, stream>>>(
        Aq, Ak, Av, WtQ, WtK, WtV, bq, bk, bv, Qbf, Kbf, Vt, spp, Ws1, mp1);

    mlp2_part_kernel<<<dim3(4, 4, BB), 256, 0, stream>>>(mp1, bs1, Ws2, mp2);

    attn_mfma_kernel<<<dim3(16, NHH, BB), 256, 0, stream>>>(
        Qbf, Kbf, Vt, msbh, mp2, bs2, ctxbf);

    gemm_o_kernel<<<dim3(16, 32), 256, 0, stream>>>(ctxbf, WtO, bo, Obuf);

    ln_kernel<<<dim3(BB * SS), 256, 0, stream>>>(Obuf, query, lng, lnb, out);
}

// Round 12
// 94.286 us; speedup vs baseline: 1.0304x; 1.0304x over previous
//
#include <hip/hip_runtime.h>
#include <math.h>

// Problem constants
#define BB   2
#define SS   1024
#define HH   1024
#define NHH  16
#define SPc  0.05f
#define EPSc 1e-5f

typedef unsigned short u16;
typedef unsigned int   u32;
using bf16x8 = __attribute__((ext_vector_type(8))) __bf16;
using f32x4  = __attribute__((ext_vector_type(4))) float;

// round-to-nearest-even fp32 -> bf16 bits (finite values only)
__device__ __forceinline__ u16 f2bf(float f) {
    u32 u = __builtin_bit_cast(u32, f);
    u32 r = u + 0x7fffu + ((u >> 16) & 1u);
    return (u16)(r >> 16);
}

// async global->LDS, 16B per lane. lds must be the wave-uniform base
// (HW writes base + lane*16); g is the per-lane global source.
__device__ __forceinline__ void async16(void* lds, const void* g) {
    __builtin_amdgcn_global_load_lds((const __attribute__((address_space(1))) u32*)g,
                                     (__attribute__((address_space(3))) u32*)lds,
                                     16, 0, 0);
}

__device__ __forceinline__ bf16x8 ldb8(const u16* p) {
    return *(const bf16x8*)(const void*)p;
}

// ---------------------------------------------------------------------------
// PREP (one launch, flat grid of 7248 blocks x 256):
//   [0,6144)      conv_a: q/k/v fp32 -> bf16
//   [6144,7168)   conv_w: W fp32 [k][n] -> bf16 Wt [n][k] (4 weights x 256 tiles)
//   [7168,7184)   msb per-head mean
//   [7184,7248)   seqmean partials of query
// ---------------------------------------------------------------------------
__global__ __launch_bounds__(256) void prep_kernel(
    const float* __restrict__ query, const float* __restrict__ key_t,
    const float* __restrict__ value,
    u16* __restrict__ Aq, u16* __restrict__ Ak, u16* __restrict__ Av,
    const float* __restrict__ W0, const float* __restrict__ W1,
    const float* __restrict__ W2, const float* __restrict__ W3,
    u16* __restrict__ T0, u16* __restrict__ T1,
    u16* __restrict__ T2, u16* __restrict__ T3,
    const float* __restrict__ msb, float* __restrict__ msbh,
    float* __restrict__ spp) {
    const int t = threadIdx.x;
    const int d = blockIdx.x;

    if (d < 6144) {                       // ---- conv_a ----
        const int which = d >> 11;
        const int bx    = d & 2047;
        const float* s; u16* dst;
        if (which == 0)      { s = query; dst = Aq; }
        else if (which == 1) { s = key_t; dst = Ak; }
        else                 { s = value; dst = Av; }
        const size_t i = ((size_t)bx * 256 + t) * 4;
        const float4 v = *(const float4*)(s + i);
        ushort4 o;
        o.x = f2bf(v.x); o.y = f2bf(v.y); o.z = f2bf(v.z); o.w = f2bf(v.w);
        *(ushort4*)(dst + i) = o;
        return;
    }
    if (d < 7168) {                       // ---- conv_w ----
        const int e  = d - 6144;
        const int wz = e >> 8;
        const int k0 = ((e >> 4) & 15) << 6;
        const int n0 = (e & 15) << 6;
        const float* W; u16* T;
        if (wz == 0)      { W = W0; T = T0; }
        else if (wz == 1) { W = W1; T = T1; }
        else if (wz == 2) { W = W2; T = T2; }
        else              { W = W3; T = T3; }
        __shared__ u16 tile[64][72];
        #pragma unroll
        for (int i = 0; i < 4; ++i) {
            const int chunk = i * 256 + t;
            const int r  = chunk >> 4;
            const int c4 = (chunk & 15) << 2;
            const float4 v = *(const float4*)(W + (size_t)(k0 + r) * 1024 + n0 + c4);
            tile[c4 + 0][r] = f2bf(v.x);
            tile[c4 + 1][r] = f2bf(v.y);
            tile[c4 + 2][r] = f2bf(v.z);
            tile[c4 + 3][r] = f2bf(v.w);
        }
        __syncthreads();
        #pragma unroll
        for (int i = 0; i < 4; ++i) {
            const int chunk = i * 256 + t;
            const int rn = chunk >> 4;
            const int ck = (chunk & 15) << 2;
            ushort4 o;
            o.x = tile[rn][ck + 0];
            o.y = tile[rn][ck + 1];
            o.z = tile[rn][ck + 2];
            o.w = tile[rn][ck + 3];
            *(ushort4*)(T + (size_t)(n0 + rn) * 1024 + k0 + ck) = o;
        }
        return;
    }
    if (d < 7184) {                       // ---- msb mean ----
        const int h = d - 7168;
        const float* p = msb + (size_t)h * 4096;
        float s = 0.f;
        for (int i = t; i < 4096; i += 256) s += p[i];
        __shared__ float red[256];
        red[t] = s;
        __syncthreads();
        for (int off = 128; off > 0; off >>= 1) {
            if (t < off) red[t] += red[t + off];
            __syncthreads();
        }
        if (t == 0) msbh[h] = red[0] * (1.f / 4096.f);
        return;
    }
    {                                     // ---- seqmean partials ----
        const int e = d - 7184;           // x:4, b:2, z:8
        const int x = e & 3;
        const int b = (e >> 2) & 1;
        const int z = e >> 3;
        const int h = x * 256 + t;
        const float* p = query + ((size_t)b * SS + (size_t)z * 128) * HH + h;
        float s = 0.f;
        for (int i = 0; i < 128; ++i) s += p[(size_t)i * HH];
        spp[((size_t)z * BB + b) * HH + h] = s;
    }
}

// ---------------------------------------------------------------------------
// spec MLP layer 2 (h1 finish fused): block (oc, kc2, b). Writes partial
// pre-bias dots; attn adds bs2 + sigmoid + mean.
// ---------------------------------------------------------------------------
__global__ __launch_bounds__(256) void mlp2_part_kernel(
    const float* __restrict__ mp1, const float* __restrict__ bs1,
    const float* __restrict__ Ws2, float* __restrict__ mp2) {
    const int t   = threadIdx.x;
    const int oc  = blockIdx.x;
    const int kc2 = blockIdx.y;
    const int b   = blockIdx.z;
    __shared__ float x[128];
    if (t < 128) {
        const int j = kc2 * 128 + t;
        float a = bs1[j];
        #pragma unroll
        for (int kc = 0; kc < 8; ++kc) a += mp1[((size_t)kc * BB + b) * 512 + j];
        x[t] = fmaxf(a, 0.f);
    }
    __syncthreads();
    const int o = oc * 256 + t;
    float acc = 0.f;
    #pragma unroll 4
    for (int k2 = 0; k2 < 128; ++k2)
        acc += x[k2] * Ws2[(size_t)(kc2 * 128 + k2) * 1024 + o];
    mp2[((size_t)kc2 * BB + b) * 1024 + o] = acc;
}

// ---------------------------------------------------------------------------
// bf16 MFMA GEMM core: tile BM x BN, BK=32, 4 waves (2m x 2n).
// TRIPLE-buffered LDS + counted s_waitcnt vmcnt(N) + raw s_barrier:
// next-tile loads stay in flight across the barrier (never drain to 0 in
// the main loop). Safety: stage(kk+1) writes buf[(kk+1)%3], last read at
// compute(kk-2) which all waves finished before barrier(kk-1).
// Swizzle: LDS chunk (r,c) holds data chunk (r, c^((r>>1)&3)).
// mode: 0 = f32 out row-major, 1 = bf16 out row-major, 2 = bf16 out -> Vt[b,h,d,s]
// ---------------------------------------------------------------------------
template<int BM, int BN>
__device__ __forceinline__ void gemm_core(const u16* __restrict__ A,
                                          const u16* __restrict__ Bt,
                                          const float* __restrict__ bias,
                                          void* __restrict__ Cout, int mode,
                                          int m0, int n0) {
    constexpr int FI = BM / 32;       // m-frags per wave
    constexpr int FJ = BN / 32;       // n-frags per wave
    constexpr int NL = BM / 64 + BN / 64;   // async16 instrs per thread per stage
    __shared__ u16 sA[3][BM * 32];
    __shared__ u16 sB[3][BN * 32];
    const int t  = threadIdx.x;
    const int l  = t & 63;
    const int wv = t >> 6;
    const int wm = wv >> 1, wn = wv & 1;
    const int wbase = t & ~63;
    const int ql = l & 15;
    const int g_ = l >> 4;

    f32x4 acc[FI][FJ];
    #pragma unroll
    for (int i = 0; i < FI; ++i)
        #pragma unroll
        for (int j = 0; j < FJ; ++j) acc[i][j] = (f32x4){0.f, 0.f, 0.f, 0.f};

    auto stage = [&](int buf, int k0) {
        #pragma unroll
        for (int ii = 0; ii < BM / 64; ++ii) {
            const int chunk = ii * 256 + t;
            const int r  = chunk >> 2, c = chunk & 3;
            const int cs = (c ^ ((r >> 1) & 3)) << 3;
            async16(&sA[buf][(ii * 256 + wbase) << 3],
                    A + (size_t)(m0 + r) * 1024 + k0 + cs);
        }
        #pragma unroll
        for (int ii = 0; ii < BN / 64; ++ii) {
            const int chunk = ii * 256 + t;
            const int r  = chunk >> 2, c = chunk & 3;
            const int cs = (c ^ ((r >> 1) & 3)) << 3;
            async16(&sB[buf][(ii * 256 + wbase) << 3],
                    Bt + (size_t)(n0 + r) * 1024 + k0 + cs);
        }
    };

    stage(0, 0);
    for (int kk = 0; kk < 32; ++kk) {
        const int cur = kk % 3;
        if (kk < 31) {
            stage((kk + 1) % 3, (kk + 1) << 5);
            asm volatile("s_waitcnt vmcnt(%0)" :: "i"(NL) : "memory");
        } else {
            asm volatile("s_waitcnt vmcnt(0)" ::: "memory");
        }
        __builtin_amdgcn_s_barrier();
        const u16* bufA = sA[cur];
        const u16* bufB = sB[cur];
        bf16x8 af[FI], bg[FJ];
        #pragma unroll
        for (int i = 0; i < FI; ++i) {
            const int ra = wm * (BM / 2) + i * 16 + ql;
            af[i] = ldb8(bufA + ra * 32 + (((g_ ^ ((ra >> 1) & 3))) << 3));
        }
        #pragma unroll
        for (int j = 0; j < FJ; ++j) {
            const int rb = wn * (BN / 2) + j * 16 + ql;
            bg[j] = ldb8(bufB + rb * 32 + (((g_ ^ ((rb >> 1) & 3))) << 3));
        }
        __builtin_amdgcn_s_setprio(1);
        #pragma unroll
        for (int i = 0; i < FI; ++i)
            #pragma unroll
            for (int j = 0; j < FJ; ++j)
                acc[i][j] = __builtin_amdgcn_mfma_f32_16x16x32_bf16(af[i], bg[j], acc[i][j], 0, 0, 0);
        __builtin_amdgcn_s_setprio(0);
    }

    // epilogue: C/D layout col=lane&15, row=(lane>>4)*4+reg
    const int coll = ql;
    const int rowg = g_ << 2;
    #pragma unroll
    for (int j = 0; j < FJ; ++j) {
        const int n = n0 + wn * (BN / 2) + j * 16 + coll;
        const float bs = bias[n];
        #pragma unroll
        for (int i = 0; i < FI; ++i) {
            const int mb = m0 + wm * (BM / 2) + i * 16 + rowg;
            if (mode == 0) {
                float* C = (float*)Cout;
                #pragma unroll
                for (int rr = 0; rr < 4; ++rr)
                    C[(size_t)(mb + rr) * 1024 + n] = acc[i][j][rr] + bs;
            } else if (mode == 1) {
                u16* C = (u16*)Cout;
                #pragma unroll
                for (int rr = 0; rr < 4; ++rr)
                    C[(size_t)(mb + rr) * 1024 + n] = f2bf(acc[i][j][rr] + bs);
            } else {
                // Vt[b][h=n>>6][d=n&63][s=mb..mb+3], 4 consecutive s -> 8B store
                u16* C = (u16*)Cout;
                const int bI = mb >> 10;
                const int s  = mb & 1023;
                ushort4 o;
                o.x = f2bf(acc[i][j][0] + bs);
                o.y = f2bf(acc[i][j][1] + bs);
                o.z = f2bf(acc[i][j][2] + bs);
                o.w = f2bf(acc[i][j][3] + bs);
                *(ushort4*)(C + ((size_t)(bI * NHH + (n >> 6)) * 64 + (n & 63)) * 1024 + s) = o;
            }
        }
    }
}

// QKV GEMM (768 blocks, XCD-chunked) + mlp1 (32 trailing blocks).
__global__ __launch_bounds__(256, 3) void gemm_qkv_kernel(
    const u16* __restrict__ Aq, const u16* __restrict__ Ak, const u16* __restrict__ Av,
    const u16* __restrict__ WtQ, const u16* __restrict__ WtK, const u16* __restrict__ WtV,
    const float* __restrict__ bq, const float* __restrict__ bk, const float* __restrict__ bv,
    u16* __restrict__ Qbf, u16* __restrict__ Kbf, u16* __restrict__ Vt,
    const float* __restrict__ spp, const float* __restrict__ Ws1,
    float* __restrict__ mp1) {
    const int d = (int)blockIdx.x;
    if (d >= 768) {                       // ---- mlp1 partials ----
        const int e  = d - 768;           // jc:2, kc:8, b:2
        const int jc = e & 1;
        const int kc = (e >> 1) & 7;
        const int b  = e >> 4;
        const int t  = threadIdx.x;
        __shared__ float x[128];
        if (t < 128) {
            const int k = kc * 128 + t;
            float s = 0.f;
            #pragma unroll
            for (int z = 0; z < 8; ++z) s += spp[((size_t)z * BB + b) * HH + k];
            x[t] = s * (1.f / (float)SS);
        }
        __syncthreads();
        const int j = jc * 256 + t;
        float acc = 0.f;
        #pragma unroll 4
        for (int k2 = 0; k2 < 128; ++k2)
            acc += x[k2] * Ws1[(size_t)(kc * 128 + k2) * 512 + j];
        mp1[((size_t)kc * BB + b) * 512 + j] = acc;
        return;
    }
    const int g = (d & 7) * 96 + (d >> 3);       // bijective: 768 = 8 * 96
    const int n0 = (g & 7) << 7;
    const int m0 = ((g >> 3) & 31) << 6;
    const int zz = g >> 8;
    if (zz == 0)      gemm_core<64, 128>(Aq, WtQ, bq, Qbf, 1, m0, n0);
    else if (zz == 1) gemm_core<64, 128>(Ak, WtK, bk, Kbf, 1, m0, n0);
    else              gemm_core<64, 128>(Av, WtV, bv, Vt, 2, m0, n0);
}

// O-proj: BM=64, BN=64, grid 512 blocks, XCD-chunked swizzle.
__global__ __launch_bounds__(256, 3) void gemm_o_kernel(
    const u16* __restrict__ A, const u16* __restrict__ Bt,
    const float* __restrict__ bias, float* __restrict__ C) {
    const int d = (int)blockIdx.x + ((int)blockIdx.y << 4);
    const int g = (d & 7) * 64 + (d >> 3);       // bijective: 512 = 8 * 64
    const int n0 = (g & 15) << 6;
    const int m0 = (g >> 4) << 6;
    gemm_core<64, 64>(A, Bt, bias, C, 0, m0, n0);
}

// ---------------------------------------------------------------------------
// Flash attention, bf16 MFMA, swapped QK^T, IN-REGISTER P (permuted K rows).
// 4 waves x 16 q rows (QBLK=64). Triple-buffered K/V + counted vmcnt + raw
// barrier (loads span barriers). Per-wave spec reduce (no barriers).
// Gate+scale folded to quartic: v = A*raw + B*raw^2 - D*raw^4.
// Grid (S/64, NH, B) = 512 blocks, 256 threads.
// ---------------------------------------------------------------------------
__global__ __launch_bounds__(256, 2) void attn_mfma_kernel(
    const u16* __restrict__ Qbf, const u16* __restrict__ Kbf,
    const u16* __restrict__ Vt, const float* __restrict__ msbh,
    const float* __restrict__ mp2, const float* __restrict__ bs2,
    u16* __restrict__ ctx) {
    __shared__ u16 sK[3][4096];
    __shared__ u16 sV[3][4096];

    const int t  = threadIdx.x;     // 0..255
    const int l  = t & 63;
    const int wv = t >> 6;          // 0..3
    const int wbase = t & ~63;
    const int qt = blockIdx.x, h = blockIdx.y, b = blockIdx.z;
    const int ql = l & 15;          // this lane's q row (within wave's 16)
    const int g_ = l >> 4;          // lane group 0..3

    const u16* Kg = Kbf + (size_t)b * SS * HH + h * 64;
    const u16* Vg = Vt + (size_t)(b * NHH + h) * 64 * SS;   // rows d, cols s

    // Q fragments direct from global (L2-resident)
    const u16* qrow = Qbf + ((size_t)(b * SS + qt * 64 + wv * 16 + ql)) * HH + h * 64;
    const bf16x8 qf0 = ldb8(qrow + (g_ << 3));
    const bf16x8 qf1 = ldb8(qrow + ((4 + g_) << 3));

    // staging offsets (constant across kt); 2 chunks per thread per K and V
    int koff[2], vof[2], lof[2];
    #pragma unroll
    for (int ii = 0; ii < 2; ++ii) {
        const int chunk = ii * 256 + t;
        const int r = chunk >> 3, c = chunk & 7;
        // perm: LDS row r holds K seq row perm(r) (PV k-sum is perm-invariant)
        const int rp = (r & 3) | (((r >> 2) & 3) << 3) | (((r >> 4) & 1) << 2) | (r & 32);
        const int cs = (c ^ (r & 7)) << 3;
        koff[ii] = rp * 1024 + cs;
        vof[ii]  = r * 1024 + cs;
        lof[ii]  = (ii * 256 + wbase) << 3;
    }

#define KVSTAGE(buf, kt)                                                        \
    {                                                                           \
        _Pragma("unroll")                                                       \
        for (int ii = 0; ii < 2; ++ii) {                                        \
            async16(sK[buf] + lof[ii], Kg + ((size_t)(kt) << 16) + koff[ii]);   \
            async16(sV[buf] + lof[ii], Vg + ((kt) << 6) + vof[ii]);             \
        }                                                                       \
    }

    KVSTAGE(0, 0)

    // ---- per-wave spec: mean over o of sigmoid(sum_kc mp2 + bs2) ----
    float ssum = 0.f;
    #pragma unroll
    for (int j = 0; j < 16; ++j) {
        const int o = (j << 6) + l;
        float a = bs2[o];
        #pragma unroll
        for (int kc = 0; kc < 4; ++kc) a += mp2[((size_t)kc * BB + b) * 1024 + o];
        ssum += 1.f / (1.f + __expf(-a));
    }
    #pragma unroll
    for (int off = 1; off < 64; off <<= 1) ssum += __shfl_xor(ssum, off);
    const float sp = ssum * (1.f / 1024.f);

    const float mh = msbh[h] * 0.125f;
    const float c2 = 0.125f * sp;
    const float c3 = 0.125f * sp * SPc;
    // v = raw*(c2 + c3*sigmoid(raw*mh)); sigmoid(x) ~= 0.5 + 0.25x - x^3/48
    // => v = Ac*raw + Bc*raw^2 - Dc*raw^4
    const float Ac = c2 + 0.5f * c3;
    const float Bc = 0.25f * c3 * mh;
    const float Dc = c3 * mh * mh * mh * (1.f / 48.f);

    f32x4 oacc[4];
    #pragma unroll
    for (int dt = 0; dt < 4; ++dt) oacc[dt] = (f32x4){0.f, 0.f, 0.f, 0.f};
    float lsum = 0.f;

    for (int kt = 0; kt < 16; ++kt) {
        const int cur = kt % 3;
        if (kt < 15) {
            KVSTAGE((kt + 1) % 3, kt + 1)
            asm volatile("s_waitcnt vmcnt(4)" ::: "memory");
        } else {
            asm volatile("s_waitcnt vmcnt(0)" ::: "memory");
        }
        __builtin_amdgcn_s_barrier();

        const u16* bufK = sK[cur];
        const u16* bufV = sV[cur];

        // swapped QK^T: lane holds S[k-slots][q=ql]
        f32x4 sc[4];
        __builtin_amdgcn_s_setprio(1);
        #pragma unroll
        for (int f = 0; f < 4; ++f) {
            const int r = (f << 4) + ql;
            bf16x8 kfa = ldb8(bufK + r * 64 + ((g_ ^ (r & 7)) << 3));
            bf16x8 kfb = ldb8(bufK + r * 64 + (((4 + g_) ^ (r & 7)) << 3));
            f32x4 z = (f32x4){0.f, 0.f, 0.f, 0.f};
            z = __builtin_amdgcn_mfma_f32_16x16x32_bf16(kfa, qf0, z, 0, 0, 0);
            z = __builtin_amdgcn_mfma_f32_16x16x32_bf16(kfb, qf1, z, 0, 0, 0);
            sc[f] = z;
        }
        __builtin_amdgcn_s_setprio(0);

        // quartic gate + exp; build PV A-fragments in-register
        bf16x8 pf0, pf1;
        #pragma unroll
        for (int f = 0; f < 4; ++f) {
            #pragma unroll
            for (int rr = 0; rr < 4; ++rr) {
                const float raw = sc[f][rr];
                const float r2 = raw * raw;
                const float tt = fmaf(-Dc, r2, Bc);
                const float v  = fmaf(tt, r2, Ac * raw);
                const float p  = __expf(v);
                lsum += p;
                const __bf16 pbv = (__bf16)p;
                if (f == 0)      pf0[rr] = pbv;
                else if (f == 1) pf0[4 + rr] = pbv;
                else if (f == 2) pf1[rr] = pbv;
                else             pf1[4 + rr] = pbv;
            }
        }

        // PV: O[q][d] += P * V^T (B operand = Vt rows d, s-chunks)
        __builtin_amdgcn_s_setprio(1);
        #pragma unroll
        for (int dt = 0; dt < 4; ++dt) {
            const int r = (dt << 4) + ql;
            bf16x8 vf0 = ldb8(bufV + r * 64 + ((g_ ^ (r & 7)) << 3));
            bf16x8 vf1 = ldb8(bufV + r * 64 + (((4 + g_) ^ (r & 7)) << 3));
            oacc[dt] = __builtin_amdgcn_mfma_f32_16x16x32_bf16(pf0, vf0, oacc[dt], 0, 0, 0);
            oacc[dt] = __builtin_amdgcn_mfma_f32_16x16x32_bf16(pf1, vf1, oacc[dt], 0, 0, 0);
        }
        __builtin_amdgcn_s_setprio(0);
    }
#undef KVSTAGE

    // row sums: lanes {q, q+16, q+32, q+48} hold disjoint partials of row q
    lsum += __shfl_xor(lsum, 16);
    lsum += __shfl_xor(lsum, 32);

    float linv[4];
    #pragma unroll
    for (int rr = 0; rr < 4; ++rr) linv[rr] = 1.f / __shfl(lsum, (g_ << 2) + rr);

    // store ctx (bf16 row-major [b,s,h*64+d]); output rows m=(l>>4)*4+rr
    #pragma unroll
    for (int rr = 0; rr < 4; ++rr) {
        const int q = qt * 64 + wv * 16 + (g_ << 2) + rr;
        u16* crow = ctx + ((size_t)(b * SS + q)) * HH + h * 64;
        #pragma unroll
        for (int dt = 0; dt < 4; ++dt)
            crow[dt * 16 + ql] = f2bf(oacc[dt][rr] * linv[rr]);
    }
}

// ---------------------------------------------------------------------------
// residual + LayerNorm: out = LN(X + query) * g + b ; one block per row
// ---------------------------------------------------------------------------
__global__ __launch_bounds__(256) void ln_kernel(
    const float* __restrict__ X, const float* __restrict__ qin,
    const float* __restrict__ g, const float* __restrict__ be, float* __restrict__ out) {
    const int row = blockIdx.x;
    const int t   = threadIdx.x;
    const int d4  = t << 2;
    const float4 x4 = *(const float4*)(X + (size_t)row * HH + d4);
    const float4 q4 = *(const float4*)(qin + (size_t)row * HH + d4);
    float4 v;
    v.x = x4.x + q4.x;
    v.y = x4.y + q4.y;
    v.z = x4.z + q4.z;
    v.w = x4.w + q4.w;
    float s  = v.x + v.y + v.z + v.w;
    float sq = v.x * v.x + v.y * v.y + v.z * v.z + v.w * v.w;
    for (int off = 1; off < 64; off <<= 1) {
        s  += __shfl_xor(s, off);
        sq += __shfl_xor(sq, off);
    }
    __shared__ float rs[4], rq[4];
    const int w = t >> 6;
    if ((t & 63) == 0) { rs[w] = s; rq[w] = sq; }
    __syncthreads();
    s  = rs[0] + rs[1] + rs[2] + rs[3];
    sq = rq[0] + rq[1] + rq[2] + rq[3];
    const float mu   = s * (1.f / (float)HH);
    const float var  = sq * (1.f / (float)HH) - mu * mu;
    const float rstd = rsqrtf(var + EPSc);
    const float4 g4 = *(const float4*)(g + d4);
    const float4 b4 = *(const float4*)(be + d4);
    float4 o;
    o.x = (v.x - mu) * rstd * g4.x + b4.x;
    o.y = (v.y - mu) * rstd * g4.y + b4.y;
    o.z = (v.z - mu) * rstd * g4.z + b4.z;
    o.w = (v.w - mu) * rstd * g4.w + b4.w;
    *(float4*)(out + (size_t)row * HH + d4) = o;
}

// ---------------------------------------------------------------------------
extern "C" void kernel_launch(void* const* d_in, const int* in_sizes, int n_in,
                              void* d_out, int out_size, void* d_ws, size_t ws_size,
                              hipStream_t stream) {
    (void)in_sizes; (void)n_in; (void)out_size; (void)ws_size;
    const float* query = (const float*)d_in[0];
    const float* key_t = (const float*)d_in[1];
    const float* value = (const float*)d_in[2];
    const float* Wq  = (const float*)d_in[3];
    const float* bq  = (const float*)d_in[4];
    const float* Wk  = (const float*)d_in[5];
    const float* bk  = (const float*)d_in[6];
    const float* Wv  = (const float*)d_in[7];
    const float* bv  = (const float*)d_in[8];
    const float* msb = (const float*)d_in[9];
    const float* Ws1 = (const float*)d_in[10];
    const float* bs1 = (const float*)d_in[11];
    const float* Ws2 = (const float*)d_in[12];
    const float* bs2 = (const float*)d_in[13];
    const float* Wo  = (const float*)d_in[14];
    const float* bo  = (const float*)d_in[15];
    const float* lng = (const float*)d_in[16];
    const float* lnb = (const float*)d_in[17];
    float* out = (float*)d_out;

    // workspace carve (~36.2 MB)
    char* p = (char*)d_ws;
    u16* Aq    = (u16*)p;                 //  0- 4 MB (2M bf16)
    u16* Ak    = Aq + 2097152;            //  4- 8
    u16* Av    = Ak + 2097152;            //  8-12
    u16* WtQ   = Av + 2097152;            // 12-14 (1M bf16)
    u16* WtK   = WtQ + 1048576;           // 14-16
    u16* WtV   = WtK + 1048576;           // 16-18
    u16* WtO   = WtV + 1048576;           // 18-20
    u16* Qbf   = WtO + 1048576;           // 20-24
    u16* Kbf   = Qbf + 2097152;           // 24-28
    u16* Vt    = Kbf + 2097152;           // 28-32
    u16* ctxbf = Vt + 2097152;            // 32-36
    float* Obuf = (float*)Aq;             // reuse 0-8 MB (Aq/Ak dead after QKV GEMM)
    float* spp   = (float*)(p + 36 * 1024 * 1024);   // 16384 f
    float* mp1   = spp + 16384;           // 8*2*512 = 8192 f
    float* mp2   = mp1 + 8192;            // 4*2*1024 = 8192 f
    float* msbh  = mp2 + 8192;            // NH

    prep_kernel<<<dim3(7248), 256, 0, stream>>>(
        query, key_t, value, Aq, Ak, Av,
        Wq, Wk, Wv, Wo, WtQ, WtK, WtV, WtO, msb, msbh, spp);

    gemm_qkv_kernel<<<dim3(800), 256, 0, stream>>>(
        Aq, Ak, Av, WtQ, WtK, WtV, bq, bk, bv, Qbf, Kbf, Vt, spp, Ws1, mp1);

    mlp2_part_kernel<<<dim3(4, 4, BB), 256, 0, stream>>>(mp1, bs1, Ws2, mp2);

    attn_mfma_kernel<<<dim3(16, NHH, BB), 256, 0, stream>>>(
        Qbf, Kbf, Vt, msbh, mp2, bs2, ctxbf);

    gemm_o_kernel<<<dim3(16, 32), 256, 0, stream>>>(ctxbf, WtO, bo, Obuf);

    ln_kernel<<<dim3(BB * SS), 256, 0, stream>>>(Obuf, query, lng, lnb, out);
}